// Round 7
// baseline (1240.182 us; speedup 1.0000x reference)
//
#include <hip/hip_runtime.h>

// CANPathIntegrator — R12: hide the exchange latency (2 blocks/CU).
//
// R11 post-mortem: 7.3us/step = VALU ~2.9 (SIMD) || DS-pipe ~4-5 (per-CU,
// shared) + ~1.5-2us of MALL publish/drain/poll dead time with NOTHING to
// overlap it (1 block/CU, all 16 waves at barriers). Fix: 512 blocks x 512
// threads = 64 groups x 8 slices (64 A-rows each; per-thread matvec code
// identical to R11's verified two-pass). LDS cut to ~38.5KB by deleting
// Sh/xh + epilogue — z_seq/x_seq stored IN-LOOP from S_t (256 sincos/rot
// per block-step, trivial) — so 2 blocks/CU co-reside: while one block
// spins on the 8-way flag barrier, the other computes. All 512 blocks
// resident (capacity >= 2/CU) -> spin cannot deadlock. blockIdx%8 = slice
// = XCD -> each XCD's L2 serves only its own 128KB A-slice.
//
// Carried structure (verified R9-R11, absmax 0.0078): z_t = R(omega@S_t)z0
// (rotations commute); w never materialized (xi-contract by linearity);
// injective zxc swizzle rofs(r)=12r+4*((r>>3)&7)+32*(r>>6); 17-shfl
// halving reduction; relaxed MALL atomics, seq-flag barrier, part[]
// double-buffered by t&1.

namespace {
constexpr int NT  = 128;   // time steps
constexpr int DD  = 512;   // latent dim
constexpr int KP  = 256;   // rotation pairs
constexpr int NS  = 8;     // row slices (64 rows each)
constexpr int NG  = 64;    // batch groups
constexpr int NB  = 8;     // batches per group
constexpr int NBLK = NG * NS;  // 512 blocks, 2 per CU
constexpr size_t SEQ_BYTES = (size_t)NG * NS * 16 * 4;   // 32 KB

__device__ __forceinline__ int rofs(int r) {   // injective swizzled offset
    return 12 * r + 4 * ((r >> 3) & 7) + 32 * (r >> 6);
}
}

struct __align__(16) Shm {
    float  zxc[6400];          // 25600 B  row r at rofs(r), 8 batches
    float2 dpi[NB][NT];        //  8192 B
    float2 om[KP];             //  2048 B
    float2 v[KP];              //  2048 B  normalized z0_base pairs
    float  wred[8][16];        //   512 B  per-wave reduced d partials
    float2 x[NB];              // current x (redundant per slice, identical)
    float  Sb[NB][2];          // S_t broadcast for in-loop z-store
    float  nred[8];
};   // ~38.6 KB -> 2 blocks/CU

__global__ __launch_bounds__(512) void can_main(
    const float* __restrict__ dx_pi, const float* __restrict__ z0,
    const float* __restrict__ x0, const float* __restrict__ omega,
    const float* __restrict__ A, const float* __restrict__ z0b,
    float* __restrict__ d_out,
    unsigned* __restrict__ seq, float* __restrict__ part)
{
    __shared__ Shm sh;
    const int tid = threadIdx.x;
    const int g   = blockIdx.x >> 3;    // batch group
    const int s   = blockIdx.x & 7;     // row slice: rows 64s..64s+63 (=XCD)
    const int b0  = NB * g;

    float* z_seq = d_out;
    float* x_seq = d_out + (size_t)512 * NT * DD;

    // ---- preloads ----
    #pragma unroll
    for (int it = 0; it < 2; ++it) {
        int idx = tid + (it << 9);
        int bb = idx >> 7, tt = idx & 127;
        sh.dpi[bb][tt] =
            reinterpret_cast<const float2*>(dx_pi)[(size_t)(b0 + bb) * NT + tt];
    }
    if (tid < KP) sh.om[tid] = reinterpret_cast<const float2*>(omega)[tid];

    // ||z0_base|| -> normalize once (rotation-invariant)
    float sq = 0.f;
    { float f = z0b[tid]; sq = f * f; }          // tid covers D=512 exactly
    #pragma unroll
    for (int o = 1; o < 64; o <<= 1) sq += __shfl_xor(sq, o, 64);
    if ((tid & 63) == 0) sh.nred[tid >> 6] = sq;
    __syncthreads();
    float nsq = 0.f;
    #pragma unroll
    for (int w = 0; w < 8; ++w) nsq += sh.nred[w];
    const float zinv = 1.0f / (sqrtf(nsq) + 1e-5f);
    if (tid < KP) {
        float2 vv = reinterpret_cast<const float2*>(z0b)[tid];
        sh.v[tid] = make_float2(vv.x * zinv, vv.y * zinv);
    }

    // persistent x / S state: thread v<16 owns (b = v&7, comp = v>>3)
    float xreg = 0.f, Sreg = 0.f;
    if (tid < 16) {
        int b = tid & 7, comp = tid >> 3;
        xreg = x0[(size_t)(b0 + b) * 2 + comp];
        reinterpret_cast<float*>(&sh.x[b])[comp] = xreg;
    }

    // in-loop z-store constants: thread tid<256 owns (b = tid>>5, kk = tid&31)
    float2 z0p = make_float2(0.f, 0.f), omz = make_float2(0.f, 0.f);
    const int zsb = tid >> 5, zsk = tid & 31;
    if (tid < 256) {
        z0p = reinterpret_cast<const float2*>(z0)
                  [(size_t)(b0 + zsb) * KP + 32 * s + zsk];
        omz = reinterpret_cast<const float2*>(omega)[32 * s + zsk];
    }
    __syncthreads();

    // role constants (identical per-thread shape to R11)
    const int rq  = tid >> 6;            // row chunk: rows 8rq..8rq+7 of slice
    const int cq  = tid & 63;            // col oct:   cols 8cq..8cq+7
    const int rg0 = 64 * s + 8 * rq;     // first global row
    const float4* Ap = reinterpret_cast<const float4*>(A)
                       + (size_t)rg0 * 128 + 2 * cq;
    const int zb  = rofs(rg0);           // +12 per row (same 8-block)
    const int c0  = 8 * cq;
    const int lane = tid & 63;
    const int s5 = (lane >> 5) & 1, s4 = (lane >> 4) & 1;
    const int s3 = (lane >> 3) & 1, s2 = (lane >> 2) & 1;

    unsigned* seqp = seq + (g * 8 + s) * 16;

    for (int t = 0; t < NT; ++t) {
        // ---- P1: zx rows (pair k1, batch-quad h4) = T(omega@x) z0hat ----
        {
            int k1 = tid & 255, h4 = tid >> 8;
            float2 o2 = sh.om[k1];
            float2 vv = sh.v[k1];
            int ro0 = rofs(2 * k1);      // rofs(2k1+1) = ro0 + 12
            float c0v[4], c1v[4];
            #pragma unroll
            for (int j = 0; j < 4; ++j) {
                float2 xb = sh.x[4 * h4 + j];
                float th = o2.x * xb.x + o2.y * xb.y;
                float sn, cs;
                __sincosf(th, &sn, &cs);
                c0v[j] = cs * vv.x - sn * vv.y;
                c1v[j] = sn * vv.x + cs * vv.y;
            }
            *reinterpret_cast<float4*>(&sh.zxc[ro0 + 4 * h4]) =
                make_float4(c0v[0], c0v[1], c0v[2], c0v[3]);
            *reinterpret_cast<float4*>(&sh.zxc[ro0 + 12 + 4 * h4]) =
                make_float4(c1v[0], c1v[1], c1v[2], c1v[3]);
        }
        __syncthreads();

        // ---- P2 + contract in two column-half passes (verified R11) ----
        #pragma unroll
        for (int h = 0; h < 2; ++h) {
            float4 accA[4], accB[4];
            #pragma unroll
            for (int c = 0; c < 4; ++c) {
                accA[c] = make_float4(0.f, 0.f, 0.f, 0.f);
                accB[c] = make_float4(0.f, 0.f, 0.f, 0.f);
            }
            #pragma unroll
            for (int jr = 0; jr < 8; ++jr) {
                float4 a = Ap[(size_t)jr * 128 + h];
                float4 zA = *reinterpret_cast<const float4*>(
                                &sh.zxc[zb + 12 * jr]);
                float4 zB = *reinterpret_cast<const float4*>(
                                &sh.zxc[zb + 12 * jr + 4]);
                float aw[4];
                aw[0] = a.x; aw[1] = a.y; aw[2] = a.z; aw[3] = a.w;
                #pragma unroll
                for (int c = 0; c < 4; ++c) {
                    accA[c].x = fmaf(aw[c], zA.x, accA[c].x);
                    accA[c].y = fmaf(aw[c], zA.y, accA[c].y);
                    accA[c].z = fmaf(aw[c], zA.z, accA[c].z);
                    accA[c].w = fmaf(aw[c], zA.w, accA[c].w);
                    accB[c].x = fmaf(aw[c], zB.x, accB[c].x);
                    accB[c].y = fmaf(aw[c], zB.y, accB[c].y);
                    accB[c].z = fmaf(aw[c], zB.z, accB[c].z);
                    accB[c].w = fmaf(aw[c], zB.w, accB[c].w);
                }
            }

            float4 d0A = make_float4(0,0,0,0), d0B = d0A;
            float4 d1A = d0A, d1B = d0A;
            float4 omv = *reinterpret_cast<const float4*>(
                             &sh.om[4 * cq + 2 * h]);
            #pragma unroll
            for (int pp = 0; pp < 2; ++pp) {
                int rl = rofs(c0 + 4 * h + 2 * pp);  // even row; odd = +12
                float4 zl0 = *reinterpret_cast<const float4*>(&sh.zxc[rl]);
                float4 zl1 = *reinterpret_cast<const float4*>(&sh.zxc[rl + 4]);
                float4 zh0 = *reinterpret_cast<const float4*>(&sh.zxc[rl + 12]);
                float4 zh1 = *reinterpret_cast<const float4*>(&sh.zxc[rl + 16]);
                float4 wl = accA[2 * pp], wh = accA[2 * pp + 1];
                float4 gl = accB[2 * pp], gh = accB[2 * pp + 1];
                float4 gA, gB;
                gA.x = fmaf(wh.x, zl0.x, -wl.x * zh0.x);
                gA.y = fmaf(wh.y, zl0.y, -wl.y * zh0.y);
                gA.z = fmaf(wh.z, zl0.z, -wl.z * zh0.z);
                gA.w = fmaf(wh.w, zl0.w, -wl.w * zh0.w);
                gB.x = fmaf(gh.x, zl1.x, -gl.x * zh1.x);
                gB.y = fmaf(gh.y, zl1.y, -gl.y * zh1.y);
                gB.z = fmaf(gh.z, zl1.z, -gl.z * zh1.z);
                gB.w = fmaf(gh.w, zl1.w, -gl.w * zh1.w);
                float ox = pp ? omv.z : omv.x;
                float oy = pp ? omv.w : omv.y;
                d0A.x = fmaf(gA.x, ox, d0A.x); d1A.x = fmaf(gA.x, oy, d1A.x);
                d0A.y = fmaf(gA.y, ox, d0A.y); d1A.y = fmaf(gA.y, oy, d1A.y);
                d0A.z = fmaf(gA.z, ox, d0A.z); d1A.z = fmaf(gA.z, oy, d1A.z);
                d0A.w = fmaf(gA.w, ox, d0A.w); d1A.w = fmaf(gA.w, oy, d1A.w);
                d0B.x = fmaf(gB.x, ox, d0B.x); d1B.x = fmaf(gB.x, oy, d1B.x);
                d0B.y = fmaf(gB.y, ox, d0B.y); d1B.y = fmaf(gB.y, oy, d1B.y);
                d0B.z = fmaf(gB.z, ox, d0B.z); d1B.z = fmaf(gB.z, oy, d1B.z);
                d0B.w = fmaf(gB.w, ox, d0B.w); d1B.w = fmaf(gB.w, oy, d1B.w);
            }

            // 17-shfl halving reduction; lane 4j ends owning value j
            {
                float r_[16];
                *reinterpret_cast<float4*>(&r_[0])  = d0A;
                *reinterpret_cast<float4*>(&r_[4])  = d0B;
                *reinterpret_cast<float4*>(&r_[8])  = d1A;
                *reinterpret_cast<float4*>(&r_[12]) = d1B;
                #pragma unroll
                for (int k = 0; k < 8; ++k) {
                    float snd = s5 ? r_[k] : r_[k + 8];
                    float rcv = __shfl_xor(snd, 32, 64);
                    r_[k] = (s5 ? r_[k + 8] : r_[k]) + rcv;
                }
                #pragma unroll
                for (int k = 0; k < 4; ++k) {
                    float snd = s4 ? r_[k] : r_[k + 4];
                    float rcv = __shfl_xor(snd, 16, 64);
                    r_[k] = (s4 ? r_[k + 4] : r_[k]) + rcv;
                }
                #pragma unroll
                for (int k = 0; k < 2; ++k) {
                    float snd = s3 ? r_[k] : r_[k + 2];
                    float rcv = __shfl_xor(snd, 8, 64);
                    r_[k] = (s3 ? r_[k + 2] : r_[k]) + rcv;
                }
                {
                    float snd = s2 ? r_[0] : r_[1];
                    float rcv = __shfl_xor(snd, 4, 64);
                    r_[0] = (s2 ? r_[1] : r_[0]) + rcv;
                }
                r_[0] += __shfl_xor(r_[0], 2, 64);
                r_[0] += __shfl_xor(r_[0], 1, 64);
                if ((lane & 3) == 0) {
                    if (h == 0) sh.wred[rq][lane >> 2] = r_[0];
                    else        sh.wred[rq][lane >> 2] += r_[0];
                }
            }
        }
        __syncthreads();

        // ---- publish: fold 8 waves, store partials, drain, bump seq ----
        float* pbuf = part + ((size_t)(t & 1) * NG + g) * (NS * 16);
        if (tid < 16) {
            float ssum = 0.f;
            #pragma unroll
            for (int w = 0; w < 8; ++w) ssum += sh.wred[w][tid];
            __hip_atomic_store(pbuf + s * 16 + tid, ssum,
                               __ATOMIC_RELAXED, __HIP_MEMORY_SCOPE_AGENT);
        }
        asm volatile("s_waitcnt vmcnt(0)" ::: "memory");
        if (tid == 0)
            __hip_atomic_store(seqp, (unsigned)(t + 1),
                               __ATOMIC_RELAXED, __HIP_MEMORY_SCOPE_AGENT);

        // ---- consume: wave 0 polls 8 seq words, reads 8x16 partials ----
        float val = 0.f;
        if (tid < 64) {
            if (tid < 8) {
                unsigned* sq2 = seq + (g * 8 + tid) * 16;
                while (__hip_atomic_load(sq2, __ATOMIC_RELAXED,
                                         __HIP_MEMORY_SCOPE_AGENT)
                       < (unsigned)(t + 1))
                    __builtin_amdgcn_s_sleep(1);
            }
            __atomic_signal_fence(__ATOMIC_ACQUIRE);
            int sl = tid >> 4, v = tid & 15;
            val = __hip_atomic_load(pbuf + sl * 16 + v,
                                    __ATOMIC_RELAXED, __HIP_MEMORY_SCOPE_AGENT)
                + __hip_atomic_load(pbuf + (sl + 4) * 16 + v,
                                    __ATOMIC_RELAXED, __HIP_MEMORY_SCOPE_AGENT);
            val += __shfl_xor(val, 16, 64);
            val += __shfl_xor(val, 32, 64);
        }
        if (tid < 16) {
            int b = tid & 7, comp = tid >> 3;
            float pi = reinterpret_cast<const float*>(&sh.dpi[b][t])[comp];
            float dtv = fmaf(0.1f, val, pi);
            Sreg += dtv;                                  // unclipped cumsum
            xreg = fminf(fmaxf(xreg + dtv, 0.f), 2.0f);   // clipped x
            reinterpret_cast<float*>(&sh.x[b])[comp] = xreg;
            sh.Sb[b][comp] = Sreg;
        }
        __syncthreads();

        // ---- in-loop outputs: z slice rows from S_t; slice 0 stores x ----
        if (tid < 256) {
            float Sx = sh.Sb[zsb][0], Sy = sh.Sb[zsb][1];
            float th = omz.x * Sx + omz.y * Sy;
            float sn, cs;
            __sincosf(th, &sn, &cs);
            reinterpret_cast<float2*>(z_seq)
                [((size_t)(b0 + zsb) * NT + t) * KP + 32 * s + zsk] =
                make_float2(cs * z0p.x - sn * z0p.y, sn * z0p.x + cs * z0p.y);
        } else if (s == 0 && tid < 264) {
            int b = tid - 256;
            reinterpret_cast<float2*>(x_seq)[(size_t)(b0 + b) * NT + t] =
                *reinterpret_cast<float2*>(&sh.x[b]);
        }
        // no barrier: next P1 writes zxc (quiescent since pre-publish),
        // reads sh.x (written before the post-consume barrier above)
    }
}

extern "C" void kernel_launch(void* const* d_in, const int* in_sizes, int n_in,
                              void* d_out, int out_size, void* d_ws, size_t ws_size,
                              hipStream_t stream) {
    (void)in_sizes; (void)n_in; (void)out_size; (void)ws_size;
    unsigned* seq = reinterpret_cast<unsigned*>(d_ws);
    float* part = reinterpret_cast<float*>(
        reinterpret_cast<char*>(d_ws) + SEQ_BYTES);
    hipMemsetAsync(d_ws, 0, SEQ_BYTES, stream);   // zero seq words
    hipLaunchKernelGGL(can_main, dim3(NBLK), dim3(512), 0, stream,
                       (const float*)d_in[0], (const float*)d_in[1],
                       (const float*)d_in[2], (const float*)d_in[3],
                       (const float*)d_in[4], (const float*)d_in[5],
                       (float*)d_out, seq, part);
}

// Round 8
// 964.742 us; speedup vs baseline: 1.2855x; 1.2855x over previous
//
#include <hip/hip_runtime.h>

// CANPathIntegrator — R13: R11 base + z-store hidden in the exchange wait.
//
// R12 post-mortem: 2 blocks/CU regressed (1240 vs 936) — co-resident
// blocks are PHASE-LOCKED by the global step cadence; both hit the
// barrier together, so nothing was hidden and the 8-way exchange cost
// more than the 4-way. Only work independent of the exchange result can
// fill the wait window. The one such item: z_seq[t-1] (needs only
// S_{t-1}). So: revert to R11's verified 4-slice/1024-thread/1-block-CU
// structure and store z_{t-1} from waves 4-11 (threads 256..767) while
// wave 0 polls the MALL flags. Deletes the epilogue + Sh/xh arrays;
// Sb is double-buffered by t&1 so readers of S_{t-1} never race the
// owners writing S_t. x_seq stored at owner-update time (16 scalars).
//
// Carried verified structure (R9-R11, absmax 0.0078): z_t = R(omega@S_t)z0
// (rotations commute); two-pass P2 (32-reg acc, no spill at VGPR=64);
// w never materialized (xi-contract by linearity); injective zxc swizzle
// rofs(r)=12r+4*((r>>3)&7)+32*(r>>6); 17-shfl halving reduction; relaxed
// MALL atomics, seq-flag barrier, part[] double-buffered by t&1; LDS pad
// >80KB pins 1 block/CU so all 256 blocks co-reside (spin-safe).

namespace {
constexpr int NT  = 128;   // time steps
constexpr int DD  = 512;   // latent dim
constexpr int KP  = 256;   // rotation pairs
constexpr int NS  = 4;     // row slices (128 rows each)
constexpr int NG  = 64;    // batch groups
constexpr int NB  = 8;     // batches per group
constexpr int NBLK = NG * NS;  // 256 = #CUs
constexpr size_t SEQ_BYTES = (size_t)NG * NS * 16 * 4;   // 16 KB

__device__ __forceinline__ int rofs(int r) {   // injective swizzled offset
    return 12 * r + 4 * ((r >> 3) & 7) + 32 * (r >> 6);
}
}

struct __align__(16) Shm {
    float  zxc[6400];          // 25600 B  row r at rofs(r), 8 batches
    float2 dpi[NB][NT];        //  8192 B
    float2 om[KP];             //  2048 B
    float2 v[KP];              //  2048 B  normalized z0_base pairs
    float  wred[16][16];       //  1024 B  per-wave reduced d partials
    float2 x[NB];              //    64 B  current x (identical per slice)
    float  Sb[2][NB][2];       //   128 B  S_t broadcast, dbuf by t&1
    float  nred[16];           //    64 B
    float  pad[11264];         // 45056 B -> total ~84.2 KB: 1 block/CU
};

__attribute__((amdgpu_flat_work_group_size(1024, 1024),
               amdgpu_waves_per_eu(4, 4)))
__global__ void can_main(
    const float* __restrict__ dx_pi, const float* __restrict__ z0,
    const float* __restrict__ x0, const float* __restrict__ omega,
    const float* __restrict__ A, const float* __restrict__ z0b,
    float* __restrict__ d_out,
    unsigned* __restrict__ seq, float* __restrict__ part)
{
    __shared__ Shm sh;
    const int tid = threadIdx.x;
    const int g   = blockIdx.x >> 2;    // batch group
    const int s   = blockIdx.x & 3;     // row slice: rows 128s..128s+127
    const int b0  = NB * g;

    float* z_seq = d_out;
    float* x_seq = d_out + (size_t)512 * NT * DD;

    if (dx_pi == nullptr) ((volatile float*)sh.pad)[0] = 1.f;  // keep pad live

    // ---- preloads ----
    {
        int bb = tid >> 7, tt = tid & 127;
        sh.dpi[bb][tt] =
            reinterpret_cast<const float2*>(dx_pi)[(size_t)(b0 + bb) * NT + tt];
    }
    if (tid < KP) sh.om[tid] = reinterpret_cast<const float2*>(omega)[tid];

    // ||z0_base|| -> normalize once (rotation-invariant)
    float sq = 0.f;
    if (tid < DD) { float f = z0b[tid]; sq = f * f; }
    #pragma unroll
    for (int o = 1; o < 64; o <<= 1) sq += __shfl_xor(sq, o, 64);
    if ((tid & 63) == 0) sh.nred[tid >> 6] = sq;
    __syncthreads();
    float nsq = 0.f;
    #pragma unroll
    for (int w = 0; w < 16; ++w) nsq += sh.nred[w];
    const float zinv = 1.0f / (sqrtf(nsq) + 1e-5f);
    if (tid < KP) {
        float2 vv = reinterpret_cast<const float2*>(z0b)[tid];
        sh.v[tid] = make_float2(vv.x * zinv, vv.y * zinv);
    }

    // persistent x / S state: thread v<16 owns (b = v&7, comp = v>>3)
    float xreg = 0.f, Sreg = 0.f;
    if (tid < 16) {
        int b = tid & 7, comp = tid >> 3;
        xreg = x0[(size_t)(b0 + b) * 2 + comp];
        reinterpret_cast<float*>(&sh.x[b])[comp] = xreg;
    }

    // z-store role (threads 256..767): task th = tid-256 -> (b, pair kk)
    float2 z0p = make_float2(0.f, 0.f), omz = make_float2(0.f, 0.f);
    const int zth = tid - 256;
    const int zsb = zth >> 6, zsk = zth & 63;     // batch, pair-in-slice
    if (tid >= 256 && tid < 768) {
        z0p = reinterpret_cast<const float2*>(z0)
                  [(size_t)(b0 + zsb) * KP + 64 * s + zsk];
        omz = sh.om[64 * s + zsk];   // om written by tid<256 earlier...
    }
    __syncthreads();
    if (tid >= 256 && tid < 768)     // re-read after barrier (ensure visible)
        omz = sh.om[64 * s + zsk];

    // role constants (identical to R11)
    const int rq  = tid >> 6;            // row chunk: rows 8rq..8rq+7 of slice
    const int cq  = tid & 63;            // col oct:   cols 8cq..8cq+7
    const int rg0 = 128 * s + 8 * rq;    // first global row
    const float4* Ap = reinterpret_cast<const float4*>(A)
                       + (size_t)rg0 * 128 + 2 * cq;
    const int zb  = rofs(rg0);           // +12 per row (same 8-block)
    const int c0  = 8 * cq;
    const int lane = tid & 63;
    const int s5 = (lane >> 5) & 1, s4 = (lane >> 4) & 1;
    const int s3 = (lane >> 3) & 1, s2 = (lane >> 2) & 1;

    unsigned* seqp = seq + (g * 4 + s) * 16;

    for (int t = 0; t < NT; ++t) {
        // ---- P1: zx row r (8 batches) = T(omega@x) z0hat ----
        {
            int k1 = tid >> 2, bq = tid & 3;
            float2 o2 = sh.om[k1];
            float2 vv = sh.v[k1];
            int ro0 = rofs(2 * k1);      // rofs(2k1+1) = ro0 + 12
            #pragma unroll
            for (int j = 0; j < 2; ++j) {
                int b = 2 * bq + j;
                float2 xb = sh.x[b];
                float th = o2.x * xb.x + o2.y * xb.y;
                float sn, cs;
                __sincosf(th, &sn, &cs);
                sh.zxc[ro0 + b]      = cs * vv.x - sn * vv.y;
                sh.zxc[ro0 + 12 + b] = sn * vv.x + cs * vv.y;
            }
        }
        __syncthreads();

        // ---- P2 + contract in two column-half passes (verified R11) ----
        #pragma unroll
        for (int h = 0; h < 2; ++h) {
            float4 accA[4], accB[4];
            #pragma unroll
            for (int c = 0; c < 4; ++c) {
                accA[c] = make_float4(0.f, 0.f, 0.f, 0.f);
                accB[c] = make_float4(0.f, 0.f, 0.f, 0.f);
            }
            #pragma unroll
            for (int jr = 0; jr < 8; ++jr) {
                float4 a = Ap[(size_t)jr * 128 + h];
                float4 zA = *reinterpret_cast<const float4*>(
                                &sh.zxc[zb + 12 * jr]);
                float4 zB = *reinterpret_cast<const float4*>(
                                &sh.zxc[zb + 12 * jr + 4]);
                float aw[4];
                aw[0] = a.x; aw[1] = a.y; aw[2] = a.z; aw[3] = a.w;
                #pragma unroll
                for (int c = 0; c < 4; ++c) {
                    accA[c].x = fmaf(aw[c], zA.x, accA[c].x);
                    accA[c].y = fmaf(aw[c], zA.y, accA[c].y);
                    accA[c].z = fmaf(aw[c], zA.z, accA[c].z);
                    accA[c].w = fmaf(aw[c], zA.w, accA[c].w);
                    accB[c].x = fmaf(aw[c], zB.x, accB[c].x);
                    accB[c].y = fmaf(aw[c], zB.y, accB[c].y);
                    accB[c].z = fmaf(aw[c], zB.z, accB[c].z);
                    accB[c].w = fmaf(aw[c], zB.w, accB[c].w);
                }
            }

            float4 d0A = make_float4(0,0,0,0), d0B = d0A;
            float4 d1A = d0A, d1B = d0A;
            float4 omv = *reinterpret_cast<const float4*>(
                             &sh.om[4 * cq + 2 * h]);
            #pragma unroll
            for (int pp = 0; pp < 2; ++pp) {
                int rl = rofs(c0 + 4 * h + 2 * pp);  // even row; odd = +12
                float4 zl0 = *reinterpret_cast<const float4*>(&sh.zxc[rl]);
                float4 zl1 = *reinterpret_cast<const float4*>(&sh.zxc[rl + 4]);
                float4 zh0 = *reinterpret_cast<const float4*>(&sh.zxc[rl + 12]);
                float4 zh1 = *reinterpret_cast<const float4*>(&sh.zxc[rl + 16]);
                float4 wl = accA[2 * pp], wh = accA[2 * pp + 1];
                float4 gl = accB[2 * pp], gh = accB[2 * pp + 1];
                float4 gA, gB;
                gA.x = fmaf(wh.x, zl0.x, -wl.x * zh0.x);
                gA.y = fmaf(wh.y, zl0.y, -wl.y * zh0.y);
                gA.z = fmaf(wh.z, zl0.z, -wl.z * zh0.z);
                gA.w = fmaf(wh.w, zl0.w, -wl.w * zh0.w);
                gB.x = fmaf(gh.x, zl1.x, -gl.x * zh1.x);
                gB.y = fmaf(gh.y, zl1.y, -gl.y * zh1.y);
                gB.z = fmaf(gh.z, zl1.z, -gl.z * zh1.z);
                gB.w = fmaf(gh.w, zl1.w, -gl.w * zh1.w);
                float ox = pp ? omv.z : omv.x;
                float oy = pp ? omv.w : omv.y;
                d0A.x = fmaf(gA.x, ox, d0A.x); d1A.x = fmaf(gA.x, oy, d1A.x);
                d0A.y = fmaf(gA.y, ox, d0A.y); d1A.y = fmaf(gA.y, oy, d1A.y);
                d0A.z = fmaf(gA.z, ox, d0A.z); d1A.z = fmaf(gA.z, oy, d1A.z);
                d0A.w = fmaf(gA.w, ox, d0A.w); d1A.w = fmaf(gA.w, oy, d1A.w);
                d0B.x = fmaf(gB.x, ox, d0B.x); d1B.x = fmaf(gB.x, oy, d1B.x);
                d0B.y = fmaf(gB.y, ox, d0B.y); d1B.y = fmaf(gB.y, oy, d1B.y);
                d0B.z = fmaf(gB.z, ox, d0B.z); d1B.z = fmaf(gB.z, oy, d1B.z);
                d0B.w = fmaf(gB.w, ox, d0B.w); d1B.w = fmaf(gB.w, oy, d1B.w);
            }

            // 17-shfl halving reduction; lane 4j ends owning value j
            {
                float r_[16];
                *reinterpret_cast<float4*>(&r_[0])  = d0A;
                *reinterpret_cast<float4*>(&r_[4])  = d0B;
                *reinterpret_cast<float4*>(&r_[8])  = d1A;
                *reinterpret_cast<float4*>(&r_[12]) = d1B;
                #pragma unroll
                for (int k = 0; k < 8; ++k) {
                    float snd = s5 ? r_[k] : r_[k + 8];
                    float rcv = __shfl_xor(snd, 32, 64);
                    r_[k] = (s5 ? r_[k + 8] : r_[k]) + rcv;
                }
                #pragma unroll
                for (int k = 0; k < 4; ++k) {
                    float snd = s4 ? r_[k] : r_[k + 4];
                    float rcv = __shfl_xor(snd, 16, 64);
                    r_[k] = (s4 ? r_[k + 4] : r_[k]) + rcv;
                }
                #pragma unroll
                for (int k = 0; k < 2; ++k) {
                    float snd = s3 ? r_[k] : r_[k + 2];
                    float rcv = __shfl_xor(snd, 8, 64);
                    r_[k] = (s3 ? r_[k + 2] : r_[k]) + rcv;
                }
                {
                    float snd = s2 ? r_[0] : r_[1];
                    float rcv = __shfl_xor(snd, 4, 64);
                    r_[0] = (s2 ? r_[1] : r_[0]) + rcv;
                }
                r_[0] += __shfl_xor(r_[0], 2, 64);
                r_[0] += __shfl_xor(r_[0], 1, 64);
                if ((lane & 3) == 0) {
                    if (h == 0) sh.wred[rq][lane >> 2] = r_[0];
                    else        sh.wred[rq][lane >> 2] += r_[0];
                }
            }
        }
        __syncthreads();

        // ---- publish (wave 0 side): fold 16 waves, store, drain, bump ----
        float* pbuf = part + ((size_t)(t & 1) * NG + g) * (NS * 16);
        if (tid < 16) {
            float ssum = 0.f;
            #pragma unroll
            for (int w = 0; w < 16; ++w) ssum += sh.wred[w][tid];
            __hip_atomic_store(pbuf + s * 16 + tid, ssum,
                               __ATOMIC_RELAXED, __HIP_MEMORY_SCOPE_AGENT);
        }

        // ---- z-store for t-1, hidden in the wait window (waves 4-11):
        //      independent of this step's exchange; reads Sb[(t-1)&1] ----
        if (t > 0 && tid >= 256 && tid < 768) {
            float Sx = sh.Sb[(t & 1) ^ 1][zsb][0];
            float Sy = sh.Sb[(t & 1) ^ 1][zsb][1];
            float th = omz.x * Sx + omz.y * Sy;
            float sn, cs;
            __sincosf(th, &sn, &cs);
            reinterpret_cast<float2*>(z_seq)
                [((size_t)(b0 + zsb) * NT + (t - 1)) * KP + 64 * s + zsk] =
                make_float2(cs * z0p.x - sn * z0p.y,
                            sn * z0p.x + cs * z0p.y);
        }

        if (tid < 16)
            asm volatile("s_waitcnt vmcnt(0)" ::: "memory");
        if (tid == 0)
            __hip_atomic_store(seqp, (unsigned)(t + 1),
                               __ATOMIC_RELAXED, __HIP_MEMORY_SCOPE_AGENT);

        // ---- consume: wave 0 polls 4 slices in parallel, reduces ----
        float val = 0.f;
        if (tid < 64) {
            int sl = tid >> 4, v = tid & 15;
            unsigned* sq2 = seq + (g * 4 + sl) * 16;
            while (__hip_atomic_load(sq2, __ATOMIC_RELAXED,
                                     __HIP_MEMORY_SCOPE_AGENT)
                   < (unsigned)(t + 1))
                __builtin_amdgcn_s_sleep(1);
            __atomic_signal_fence(__ATOMIC_ACQUIRE);
            val = __hip_atomic_load(pbuf + sl * 16 + v,
                                    __ATOMIC_RELAXED, __HIP_MEMORY_SCOPE_AGENT);
            val += __shfl_xor(val, 16, 64);
            val += __shfl_xor(val, 32, 64);
        }
        if (tid < 16) {
            int b = tid & 7, comp = tid >> 3;
            float pi = reinterpret_cast<const float*>(&sh.dpi[b][t])[comp];
            float dtv = fmaf(0.1f, val, pi);
            Sreg += dtv;                                  // unclipped cumsum
            xreg = fminf(fmaxf(xreg + dtv, 0.f), 2.0f);   // clipped x
            reinterpret_cast<float*>(&sh.x[b])[comp] = xreg;
            sh.Sb[t & 1][b][comp] = Sreg;
            if (s == 0)
                x_seq[((size_t)(b0 + b) * NT + t) * 2 + comp] = xreg;
        }
        __syncthreads();
    }

    // ---- tail: z-store for the final step t = NT-1 ----
    if (tid >= 256 && tid < 768) {
        float Sx = sh.Sb[(NT - 1) & 1][zsb][0];
        float Sy = sh.Sb[(NT - 1) & 1][zsb][1];
        float th = omz.x * Sx + omz.y * Sy;
        float sn, cs;
        __sincosf(th, &sn, &cs);
        reinterpret_cast<float2*>(z_seq)
            [((size_t)(b0 + zsb) * NT + (NT - 1)) * KP + 64 * s + zsk] =
            make_float2(cs * z0p.x - sn * z0p.y, sn * z0p.x + cs * z0p.y);
    }
}

extern "C" void kernel_launch(void* const* d_in, const int* in_sizes, int n_in,
                              void* d_out, int out_size, void* d_ws, size_t ws_size,
                              hipStream_t stream) {
    (void)in_sizes; (void)n_in; (void)out_size; (void)ws_size;
    unsigned* seq = reinterpret_cast<unsigned*>(d_ws);
    float* part = reinterpret_cast<float*>(
        reinterpret_cast<char*>(d_ws) + SEQ_BYTES);
    hipMemsetAsync(d_ws, 0, SEQ_BYTES, stream);   // zero seq words
    hipLaunchKernelGGL(can_main, dim3(NBLK), dim3(1024), 0, stream,
                       (const float*)d_in[0], (const float*)d_in[1],
                       (const float*)d_in[2], (const float*)d_in[3],
                       (const float*)d_in[4], (const float*)d_in[5],
                       (float*)d_out, seq, part);
}

// Round 9
// 790.372 us; speedup vs baseline: 1.5691x; 1.2206x over previous
//
#include <hip/hip_runtime.h>

// CANPathIntegrator — R14: R11 base + single-round-trip packed exchange.
//
// R13 post-mortem: relocating the z-store into the wait window was neutral
// (965 vs 936) — step time is pipe-throughput-bound, not idle-latency-
// bound; only REMOVING work helps. Reverted to R11's verified epilogue
// structure. This round removes serial exchange latency instead:
//  * Packed u64 publish: value = ((t+1)<<32) | float_bits, one RELAXED
//    agent atomic store per partial. The tag travels WITH the data, so
//    consumers poll their value word directly — deletes the vmcnt(0)
//    drain, the separate seq store, and the flag->data second MALL round
//    trip. Poll condition pk >= (t+1)<<32 (tag monotone).
//    Overwrite safety = same t&1 double-buffer induction as R9-R13:
//    slice s rewrites slot[t&1] first at step t+2, which requires all
//    peers' step-(t+1) publishes, which follow their step-t consumes
//    (__syncthreads orders consume loads before the next publish).
//  * P1 zxc writes vectorized (2x float2 instead of 4x b32).
//
// Carried verified structure (R9-R11, absmax 0.0078125): z_t=R(omega@S_t)z0
// (rotations commute) -> loop tracks only x,S; epilogue regenerates
// z_seq/x_seq from LDS S-history; 64 groups x 4 slices; 256KB L2-resident
// A slice per block-step; two-pass P2 (32-reg acc, no spill at VGPR=64);
// w never materialized (xi-contract by linearity); injective zxc swizzle
// rofs(r)=12r+4*((r>>3)&7)+32*(r>>6); 17-shfl halving reduction; LDS pad
// >80KB pins 1 block/CU, grid==256 CUs -> co-resident, spin-safe.

namespace {
constexpr int NT  = 128;   // time steps
constexpr int DD  = 512;   // latent dim
constexpr int KP  = 256;   // rotation pairs
constexpr int NS  = 4;     // row slices (128 rows each)
constexpr int NG  = 64;    // batch groups
constexpr int NB  = 8;     // batches per group
constexpr int NBLK = NG * NS;  // 256 = #CUs
constexpr size_t PART_BYTES = (size_t)2 * NG * NS * 16 * 8;  // 64 KB u64

__device__ __forceinline__ int rofs(int r) {   // injective swizzled offset
    return 12 * r + 4 * ((r >> 3) & 7) + 32 * (r >> 6);
}
}

struct __align__(16) Shm {
    float  zxc[6400];          // 25600 B  row r at rofs(r), 8 batches
    float2 dpi[NB][NT];        //  8192 B
    float2 om[KP];             //  2048 B
    float2 v[KP];              //  2048 B  normalized z0_base pairs
    float  wred[16][16];       //  1024 B  per-wave reduced d partials
    float  Sh[NT][NB][2];      //  8192 B  S_t history (epilogue input)
    float  xh[NT][NB][2];      //  8192 B  x_t history
    float2 x[NB];              //    64 B  current x (identical per slice)
    float  nred[16];           //    64 B
    float  pad[7168];          // 28672 B -> total ~84.1 KB: 1 block/CU
};

__attribute__((amdgpu_flat_work_group_size(1024, 1024),
               amdgpu_waves_per_eu(4, 4)))
__global__ void can_main(
    const float* __restrict__ dx_pi, const float* __restrict__ z0,
    const float* __restrict__ x0, const float* __restrict__ omega,
    const float* __restrict__ A, const float* __restrict__ z0b,
    float* __restrict__ d_out,
    unsigned long long* __restrict__ part)
{
    __shared__ Shm sh;
    const int tid = threadIdx.x;
    const int g   = blockIdx.x >> 2;    // batch group
    const int s   = blockIdx.x & 3;     // row slice: rows 128s..128s+127
    const int b0  = NB * g;

    float* z_seq = d_out;
    float* x_seq = d_out + (size_t)512 * NT * DD;

    if (dx_pi == nullptr) ((volatile float*)sh.pad)[0] = 1.f;  // keep pad live

    // ---- preloads ----
    {
        int bb = tid >> 7, tt = tid & 127;
        sh.dpi[bb][tt] =
            reinterpret_cast<const float2*>(dx_pi)[(size_t)(b0 + bb) * NT + tt];
    }
    if (tid < KP) sh.om[tid] = reinterpret_cast<const float2*>(omega)[tid];

    // ||z0_base|| -> normalize once (rotation-invariant)
    float sq = 0.f;
    if (tid < DD) { float f = z0b[tid]; sq = f * f; }
    #pragma unroll
    for (int o = 1; o < 64; o <<= 1) sq += __shfl_xor(sq, o, 64);
    if ((tid & 63) == 0) sh.nred[tid >> 6] = sq;
    __syncthreads();
    float nsq = 0.f;
    #pragma unroll
    for (int w = 0; w < 16; ++w) nsq += sh.nred[w];
    const float zinv = 1.0f / (sqrtf(nsq) + 1e-5f);
    if (tid < KP) {
        float2 vv = reinterpret_cast<const float2*>(z0b)[tid];
        sh.v[tid] = make_float2(vv.x * zinv, vv.y * zinv);
    }

    // persistent x / S state: thread v<16 owns (b = v&7, comp = v>>3)
    float xreg = 0.f, Sreg = 0.f;
    if (tid < 16) {
        int b = tid & 7, comp = tid >> 3;
        xreg = x0[(size_t)(b0 + b) * 2 + comp];
        reinterpret_cast<float*>(&sh.x[b])[comp] = xreg;
    }
    __syncthreads();

    // role constants (identical to R11)
    const int rq  = tid >> 6;            // row chunk: rows 8rq..8rq+7 of slice
    const int cq  = tid & 63;            // col oct:   cols 8cq..8cq+7
    const int rg0 = 128 * s + 8 * rq;    // first global row
    const float4* Ap = reinterpret_cast<const float4*>(A)
                       + (size_t)rg0 * 128 + 2 * cq;
    const int zb  = rofs(rg0);           // +12 per row (same 8-block)
    const int c0  = 8 * cq;
    const int lane = tid & 63;
    const int s5 = (lane >> 5) & 1, s4 = (lane >> 4) & 1;
    const int s3 = (lane >> 3) & 1, s2 = (lane >> 2) & 1;

    for (int t = 0; t < NT; ++t) {
        // ---- P1: zx rows 2k1,2k1+1 (batches 2bq,2bq+1) = T(omega@x)z0hat
        {
            int k1 = tid >> 2, bq = tid & 3;
            float2 o2 = sh.om[k1];
            float2 vv = sh.v[k1];
            int ro0 = rofs(2 * k1);      // rofs(2k1+1) = ro0 + 12
            float a0[2], a1[2];
            #pragma unroll
            for (int j = 0; j < 2; ++j) {
                float2 xb = sh.x[2 * bq + j];
                float th = o2.x * xb.x + o2.y * xb.y;
                float sn, cs;
                __sincosf(th, &sn, &cs);
                a0[j] = cs * vv.x - sn * vv.y;
                a1[j] = sn * vv.x + cs * vv.y;
            }
            *reinterpret_cast<float2*>(&sh.zxc[ro0 + 2 * bq]) =
                make_float2(a0[0], a0[1]);
            *reinterpret_cast<float2*>(&sh.zxc[ro0 + 12 + 2 * bq]) =
                make_float2(a1[0], a1[1]);
        }
        __syncthreads();

        // ---- P2 + contract in two column-half passes (verified R11) ----
        #pragma unroll
        for (int h = 0; h < 2; ++h) {
            float4 accA[4], accB[4];
            #pragma unroll
            for (int c = 0; c < 4; ++c) {
                accA[c] = make_float4(0.f, 0.f, 0.f, 0.f);
                accB[c] = make_float4(0.f, 0.f, 0.f, 0.f);
            }
            #pragma unroll
            for (int jr = 0; jr < 8; ++jr) {
                float4 a = Ap[(size_t)jr * 128 + h];
                float4 zA = *reinterpret_cast<const float4*>(
                                &sh.zxc[zb + 12 * jr]);
                float4 zB = *reinterpret_cast<const float4*>(
                                &sh.zxc[zb + 12 * jr + 4]);
                float aw[4];
                aw[0] = a.x; aw[1] = a.y; aw[2] = a.z; aw[3] = a.w;
                #pragma unroll
                for (int c = 0; c < 4; ++c) {
                    accA[c].x = fmaf(aw[c], zA.x, accA[c].x);
                    accA[c].y = fmaf(aw[c], zA.y, accA[c].y);
                    accA[c].z = fmaf(aw[c], zA.z, accA[c].z);
                    accA[c].w = fmaf(aw[c], zA.w, accA[c].w);
                    accB[c].x = fmaf(aw[c], zB.x, accB[c].x);
                    accB[c].y = fmaf(aw[c], zB.y, accB[c].y);
                    accB[c].z = fmaf(aw[c], zB.z, accB[c].z);
                    accB[c].w = fmaf(aw[c], zB.w, accB[c].w);
                }
            }

            float4 d0A = make_float4(0,0,0,0), d0B = d0A;
            float4 d1A = d0A, d1B = d0A;
            float4 omv = *reinterpret_cast<const float4*>(
                             &sh.om[4 * cq + 2 * h]);
            #pragma unroll
            for (int pp = 0; pp < 2; ++pp) {
                int rl = rofs(c0 + 4 * h + 2 * pp);  // even row; odd = +12
                float4 zl0 = *reinterpret_cast<const float4*>(&sh.zxc[rl]);
                float4 zl1 = *reinterpret_cast<const float4*>(&sh.zxc[rl + 4]);
                float4 zh0 = *reinterpret_cast<const float4*>(&sh.zxc[rl + 12]);
                float4 zh1 = *reinterpret_cast<const float4*>(&sh.zxc[rl + 16]);
                float4 wl = accA[2 * pp], wh = accA[2 * pp + 1];
                float4 gl = accB[2 * pp], gh = accB[2 * pp + 1];
                float4 gA, gB;
                gA.x = fmaf(wh.x, zl0.x, -wl.x * zh0.x);
                gA.y = fmaf(wh.y, zl0.y, -wl.y * zh0.y);
                gA.z = fmaf(wh.z, zl0.z, -wl.z * zh0.z);
                gA.w = fmaf(wh.w, zl0.w, -wl.w * zh0.w);
                gB.x = fmaf(gh.x, zl1.x, -gl.x * zh1.x);
                gB.y = fmaf(gh.y, zl1.y, -gl.y * zh1.y);
                gB.z = fmaf(gh.z, zl1.z, -gl.z * zh1.z);
                gB.w = fmaf(gh.w, zl1.w, -gl.w * zh1.w);
                float ox = pp ? omv.z : omv.x;
                float oy = pp ? omv.w : omv.y;
                d0A.x = fmaf(gA.x, ox, d0A.x); d1A.x = fmaf(gA.x, oy, d1A.x);
                d0A.y = fmaf(gA.y, ox, d0A.y); d1A.y = fmaf(gA.y, oy, d1A.y);
                d0A.z = fmaf(gA.z, ox, d0A.z); d1A.z = fmaf(gA.z, oy, d1A.z);
                d0A.w = fmaf(gA.w, ox, d0A.w); d1A.w = fmaf(gA.w, oy, d1A.w);
                d0B.x = fmaf(gB.x, ox, d0B.x); d1B.x = fmaf(gB.x, oy, d1B.x);
                d0B.y = fmaf(gB.y, ox, d0B.y); d1B.y = fmaf(gB.y, oy, d1B.y);
                d0B.z = fmaf(gB.z, ox, d0B.z); d1B.z = fmaf(gB.z, oy, d1B.z);
                d0B.w = fmaf(gB.w, ox, d0B.w); d1B.w = fmaf(gB.w, oy, d1B.w);
            }

            // 17-shfl halving reduction; lane 4j ends owning value j
            {
                float r_[16];
                *reinterpret_cast<float4*>(&r_[0])  = d0A;
                *reinterpret_cast<float4*>(&r_[4])  = d0B;
                *reinterpret_cast<float4*>(&r_[8])  = d1A;
                *reinterpret_cast<float4*>(&r_[12]) = d1B;
                #pragma unroll
                for (int k = 0; k < 8; ++k) {
                    float snd = s5 ? r_[k] : r_[k + 8];
                    float rcv = __shfl_xor(snd, 32, 64);
                    r_[k] = (s5 ? r_[k + 8] : r_[k]) + rcv;
                }
                #pragma unroll
                for (int k = 0; k < 4; ++k) {
                    float snd = s4 ? r_[k] : r_[k + 4];
                    float rcv = __shfl_xor(snd, 16, 64);
                    r_[k] = (s4 ? r_[k + 4] : r_[k]) + rcv;
                }
                #pragma unroll
                for (int k = 0; k < 2; ++k) {
                    float snd = s3 ? r_[k] : r_[k + 2];
                    float rcv = __shfl_xor(snd, 8, 64);
                    r_[k] = (s3 ? r_[k + 2] : r_[k]) + rcv;
                }
                {
                    float snd = s2 ? r_[0] : r_[1];
                    float rcv = __shfl_xor(snd, 4, 64);
                    r_[0] = (s2 ? r_[1] : r_[0]) + rcv;
                }
                r_[0] += __shfl_xor(r_[0], 2, 64);
                r_[0] += __shfl_xor(r_[0], 1, 64);
                if ((lane & 3) == 0) {
                    if (h == 0) sh.wred[rq][lane >> 2] = r_[0];
                    else        sh.wred[rq][lane >> 2] += r_[0];
                }
            }
        }
        __syncthreads();

        // ---- publish: fold 16 waves; one packed (tag|value) u64 store ----
        unsigned long long* pbuf =
            part + ((size_t)(t & 1) * NG + g) * (NS * 16);
        if (tid < 16) {
            float ssum = 0.f;
            #pragma unroll
            for (int w = 0; w < 16; ++w) ssum += sh.wred[w][tid];
            unsigned long long pk =
                (((unsigned long long)(unsigned)(t + 1)) << 32) |
                (unsigned long long)__float_as_uint(ssum);
            __hip_atomic_store(pbuf + s * 16 + tid, pk,
                               __ATOMIC_RELAXED, __HIP_MEMORY_SCOPE_AGENT);
        }

        // ---- consume: 64 lanes poll their own value word (tag carried
        //      in the same load -> single MALL round trip), then fold ----
        float val = 0.f;
        if (tid < 64) {
            int sl = tid >> 4, v = tid & 15;
            unsigned long long* addr = pbuf + sl * 16 + v;
            const unsigned long long tgt =
                ((unsigned long long)(unsigned)(t + 1)) << 32;
            unsigned long long pk;
            for (;;) {
                pk = __hip_atomic_load(addr, __ATOMIC_RELAXED,
                                       __HIP_MEMORY_SCOPE_AGENT);
                if (pk >= tgt) break;   // tag >= t+1 (monotone)
                __builtin_amdgcn_s_sleep(1);
            }
            val = __uint_as_float((unsigned)(pk & 0xffffffffull));
            val += __shfl_xor(val, 16, 64);
            val += __shfl_xor(val, 32, 64);
        }
        if (tid < 16) {
            int b = tid & 7, comp = tid >> 3;
            float pi = reinterpret_cast<const float*>(&sh.dpi[b][t])[comp];
            float dtv = fmaf(0.1f, val, pi);
            Sreg += dtv;                                  // unclipped cumsum
            xreg = fminf(fmaxf(xreg + dtv, 0.f), 2.0f);   // clipped x
            reinterpret_cast<float*>(&sh.x[b])[comp] = xreg;
            sh.Sh[t][b][comp] = Sreg;
            sh.xh[t][b][comp] = xreg;
        }
        __syncthreads();
    }

    // ---- epilogue: z_seq[b][t][slice cols] = R(omega@S_t) z0[b] ----
    {
        int th2 = tid >> 9, b = (tid >> 6) & 7, kk = tid & 63;
        float2 zp = reinterpret_cast<const float2*>(z0)
                        [(size_t)(b0 + b) * KP + 64 * s + kk];
        float2 o2 = sh.om[64 * s + kk];
        float2* zout = reinterpret_cast<float2*>(z_seq)
                       + (size_t)(b0 + b) * NT * KP + (64 * s + kk);
        for (int tt2 = th2 * 64, e = th2 * 64 + 64; tt2 < e; ++tt2) {
            float Sx = sh.Sh[tt2][b][0], Sy = sh.Sh[tt2][b][1];
            float th = o2.x * Sx + o2.y * Sy;
            float sn, cs;
            __sincosf(th, &sn, &cs);
            zout[(size_t)tt2 * KP] =
                make_float2(cs * zp.x - sn * zp.y, sn * zp.x + cs * zp.y);
        }
    }
    if (s == 0) {   // x_seq from LDS history, coalesced
        int b = tid >> 7, tt3 = tid & 127;
        float2 xv = *reinterpret_cast<const float2*>(&sh.xh[tt3][b][0]);
        reinterpret_cast<float2*>(x_seq)[(size_t)(b0 + b) * NT + tt3] = xv;
    }
}

extern "C" void kernel_launch(void* const* d_in, const int* in_sizes, int n_in,
                              void* d_out, int out_size, void* d_ws, size_t ws_size,
                              hipStream_t stream) {
    (void)in_sizes; (void)n_in; (void)out_size; (void)ws_size;
    unsigned long long* part = reinterpret_cast<unsigned long long*>(d_ws);
    // zero tags each launch (captured in the graph, replayed every run)
    hipMemsetAsync(d_ws, 0, PART_BYTES, stream);
    hipLaunchKernelGGL(can_main, dim3(NBLK), dim3(1024), 0, stream,
                       (const float*)d_in[0], (const float*)d_in[1],
                       (const float*)d_in[2], (const float*)d_in[3],
                       (const float*)d_in[4], (const float*)d_in[5],
                       (float*)d_out, part);
}

// Round 11
// 379.759 us; speedup vs baseline: 3.2657x; 2.0812x over previous
//
#include <hip/hip_runtime.h>
#include <hip/hip_fp16.h>

// CANPathIntegrator — R16 = R15 (MFMA f16x2-split matvec) + ws_size guard.
//
// R15 never ran (container died pre-dispatch). One real hazard closed:
// R15 blindly assumed ws_size >= 1.09MB for the split-A tables; if the
// workspace were smaller, conv_a faults -> spin blocks wedge the GPU ->
// exactly the observed death signature. Now kernel_launch branches on
// ws_size: MFMA path if it fits, else the PROVEN R14 f32 kernel (790us).
// The measured duration disambiguates which path ran.
//
// MFMA-path theory (R14 post-mortem: VALUBusy 79.6%, MfmaUtil 0.0 —
// VALU-bound with the matrix pipe idle; matvec = 512 v_fmac/thread/step):
//   conv_a (once/launch): Ah = f16(256*A); Al = f16((256*A - Ah)*2048).
//   P1 splits zx*256 likewise into LDS (zh, zl).
//   acc1 += Ah*zh; acc2 += Al*zh + Ah*zl; w' = acc1 + acc2/2048
//   (drop Al*zl ~2^-22 rel). x256 pre-scale keeps f16 operands normal.
//   All scales (256^2 from w, 256 from zx in the bilinear g) fold into
//   DXSC = 0.1*2^-24 at the owner update. Net ~f32-class numerics
//   (f16-direct at 2^-11 chaos-amplified; this is 2^-22).
// Shape/block: M=512 out-cols (A symmetric -> row-major), K=128 slice
// rows, N=16 (8 batches mirrored, junk cols masked). Wave w: M-tiles
// 2w,2w+1 -> 24 MFMA/step. Layouts (HW-verified m89): A[m=l&15][k=8(l>>4)+j],
// B[k=8(l>>4)+j][n=l&15], C col=l&15 row=4(l>>4)+reg.
// Contract in-register by linearity (pairs (2k,2k+1) = adjacent C regs);
// 4-shfl reduce; packed-u64 single-round-trip MALL exchange, owner update,
// and S_t/epilogue regeneration = R14 verbatim.

typedef __attribute__((ext_vector_type(8))) _Float16 half8;
typedef __attribute__((ext_vector_type(4))) float f32x4;

namespace {
constexpr int NT = 128;    // time steps
constexpr int DD = 512;    // latent dim
constexpr int KP = 256;    // rotation pairs
constexpr int NS = 4;      // row slices (128 rows each)
constexpr int NG = 64;     // batch groups
constexpr int NB = 8;      // batches per group
constexpr int NBLK = NG * NS;   // 256 = #CUs
constexpr size_t PART_BYTES = (size_t)2 * NG * NS * 16 * 8;   // 64 KB
constexpr size_t A16_BYTES  = (size_t)DD * DD * 2;            // 512 KB each
constexpr float LOSC = 1.0f / 2048.0f;        // lo-term descale
constexpr float DXSC = 0.1f / 16777216.0f;    // 0.1 * 2^-24

__device__ __forceinline__ int rofs(int r) {   // injective swizzle (f32 path)
    return 12 * r + 4 * ((r >> 3) & 7) + 32 * (r >> 6);
}
}

// ======================= MFMA path (R15) ==============================

struct __align__(16) ShmM {
    unsigned short zh[NB][528];   //  8448 B  f16 hi of 256*zx, [b][r]
    unsigned short zl[NB][528];   //  8448 B  f16 lo (x2048 residual)
    float2 dpi[NB][NT];           //  8192 B
    float2 om[KP];                //  2048 B
    float2 v[KP];                 //  2048 B  z0hat * 256
    float  wred[16][16];          //  1024 B
    float  Sh[NT][NB][2];         //  8192 B
    float  xh[NT][NB][2];         //  8192 B
    float2 x[NB];                 //    64 B
    float  nred[16];              //    64 B
    float  pad[8960];             // 35840 B -> 82560 B total: 1 block/CU
};

__global__ __launch_bounds__(512) void conv_a(
    const float* __restrict__ A,
    unsigned short* __restrict__ Ah, unsigned short* __restrict__ Al)
{
    int i = blockIdx.x * 512 + threadIdx.x;
    float a = A[i] * 256.0f;
    __half h = __float2half(a);
    float r = (a - __half2float(h)) * 2048.0f;
    Ah[i] = __half_as_ushort(h);
    Al[i] = __half_as_ushort(__float2half(r));
}

__attribute__((amdgpu_flat_work_group_size(1024, 1024),
               amdgpu_waves_per_eu(4, 4)))
__global__ void can_mfma(
    const float* __restrict__ dx_pi, const float* __restrict__ z0,
    const float* __restrict__ x0, const float* __restrict__ omega,
    const float* __restrict__ z0b, float* __restrict__ d_out,
    unsigned long long* __restrict__ part,
    const unsigned short* __restrict__ Ah,
    const unsigned short* __restrict__ Al)
{
    __shared__ ShmM sh;
    const int tid = threadIdx.x;
    const int g   = blockIdx.x >> 2;
    const int s   = blockIdx.x & 3;
    const int b0  = NB * g;

    float* z_seq = d_out;
    float* x_seq = d_out + (size_t)512 * NT * DD;

    if (dx_pi == nullptr) ((volatile float*)sh.pad)[0] = 1.f;

    {
        int bb = tid >> 7, tt = tid & 127;
        sh.dpi[bb][tt] =
            reinterpret_cast<const float2*>(dx_pi)[(size_t)(b0 + bb) * NT + tt];
    }
    if (tid < KP) sh.om[tid] = reinterpret_cast<const float2*>(omega)[tid];

    float sq = 0.f;
    if (tid < DD) { float f = z0b[tid]; sq = f * f; }
    #pragma unroll
    for (int o = 1; o < 64; o <<= 1) sq += __shfl_xor(sq, o, 64);
    if ((tid & 63) == 0) sh.nred[tid >> 6] = sq;
    __syncthreads();
    float nsq = 0.f;
    #pragma unroll
    for (int w2 = 0; w2 < 16; ++w2) nsq += sh.nred[w2];
    const float zs = 256.0f / (sqrtf(nsq) + 1e-5f);
    if (tid < KP) {
        float2 vv = reinterpret_cast<const float2*>(z0b)[tid];
        sh.v[tid] = make_float2(vv.x * zs, vv.y * zs);
    }

    float xreg = 0.f, Sreg = 0.f;
    if (tid < 16) {
        int b = tid & 7, comp = tid >> 3;
        xreg = x0[(size_t)(b0 + b) * 2 + comp];
        reinterpret_cast<float*>(&sh.x[b])[comp] = xreg;
    }
    __syncthreads();

    const int w   = tid >> 6;          // wave -> M-tiles 2w, 2w+1
    const int l   = tid & 63;
    const int cB  = l & 15;            // A-frag m / C col
    const int kg  = l >> 4;            // k-chunk 0..3
    const int bB  = l & 7;             // batch (mirrored)
    const int mt0 = 2 * w;
    const unsigned short* AhP =
        Ah + (size_t)(16 * mt0 + cB) * DD + (128 * s + 8 * kg);
    const unsigned short* AlP =
        Al + (size_t)(16 * mt0 + cB) * DD + (128 * s + 8 * kg);

    for (int t = 0; t < NT; ++t) {
        // P1: f16-split zx
        {
            int k1 = tid >> 2, bq = tid & 3;
            float2 o2 = sh.om[k1];
            float2 vv = sh.v[k1];
            #pragma unroll
            for (int j = 0; j < 2; ++j) {
                int b = 2 * bq + j;
                float2 xb = sh.x[b];
                float th = o2.x * xb.x + o2.y * xb.y;
                float sn, cs;
                __sincosf(th, &sn, &cs);
                float za  = cs * vv.x - sn * vv.y;
                float zb2 = sn * vv.x + cs * vv.y;
                __half h0 = __float2half(za);
                __half h1 = __float2half(zb2);
                unsigned l0 = __half_as_ushort(
                    __float2half((za - __half2float(h0)) * 2048.f));
                unsigned l1 = __half_as_ushort(
                    __float2half((zb2 - __half2float(h1)) * 2048.f));
                *reinterpret_cast<unsigned*>(&sh.zh[b][2 * k1]) =
                    (unsigned)__half_as_ushort(h0) |
                    ((unsigned)__half_as_ushort(h1) << 16);
                *reinterpret_cast<unsigned*>(&sh.zl[b][2 * k1]) =
                    l0 | (l1 << 16);
            }
        }
        __syncthreads();

        // P2: MFMA split-precision matvec
        f32x4 ac1[2] = {{0.f, 0.f, 0.f, 0.f}, {0.f, 0.f, 0.f, 0.f}};
        f32x4 ac2[2] = {{0.f, 0.f, 0.f, 0.f}, {0.f, 0.f, 0.f, 0.f}};
        #pragma unroll
        for (int kt = 0; kt < 4; ++kt) {
            int rg = 128 * s + 32 * kt + 8 * kg;
            half8 bh = *reinterpret_cast<const half8*>(&sh.zh[bB][rg]);
            half8 bl = *reinterpret_cast<const half8*>(&sh.zl[bB][rg]);
            #pragma unroll
            for (int mi = 0; mi < 2; ++mi) {
                half8 ah = *reinterpret_cast<const half8*>(
                               AhP + (size_t)mi * 16 * DD + 32 * kt);
                half8 al = *reinterpret_cast<const half8*>(
                               AlP + (size_t)mi * 16 * DD + 32 * kt);
                ac1[mi] = __builtin_amdgcn_mfma_f32_16x16x32_f16(
                              ah, bh, ac1[mi], 0, 0, 0);
                ac2[mi] = __builtin_amdgcn_mfma_f32_16x16x32_f16(
                              al, bh, ac2[mi], 0, 0, 0);
                ac2[mi] = __builtin_amdgcn_mfma_f32_16x16x32_f16(
                              ah, bl, ac2[mi], 0, 0, 0);
            }
        }

        // contract in-register (linear in w)
        float d0 = 0.f, d1 = 0.f;
        #pragma unroll
        for (int mi = 0; mi < 2; ++mi) {
            int cb = 16 * (mt0 + mi) + 4 * kg;
            float wv0 = fmaf(ac2[mi][0], LOSC, ac1[mi][0]);
            float wv1 = fmaf(ac2[mi][1], LOSC, ac1[mi][1]);
            float wv2 = fmaf(ac2[mi][2], LOSC, ac1[mi][2]);
            float wv3 = fmaf(ac2[mi][3], LOSC, ac1[mi][3]);
            uint2 zhp = *reinterpret_cast<const uint2*>(&sh.zh[bB][cb]);
            uint2 zlp = *reinterpret_cast<const uint2*>(&sh.zl[bB][cb]);
            float z0v = fmaf(__half2float(__ushort_as_half(
                                 (unsigned short)(zlp.x & 0xffff))), LOSC,
                             __half2float(__ushort_as_half(
                                 (unsigned short)(zhp.x & 0xffff))));
            float z1v = fmaf(__half2float(__ushort_as_half(
                                 (unsigned short)(zlp.x >> 16))), LOSC,
                             __half2float(__ushort_as_half(
                                 (unsigned short)(zhp.x >> 16))));
            float z2v = fmaf(__half2float(__ushort_as_half(
                                 (unsigned short)(zlp.y & 0xffff))), LOSC,
                             __half2float(__ushort_as_half(
                                 (unsigned short)(zhp.y & 0xffff))));
            float z3v = fmaf(__half2float(__ushort_as_half(
                                 (unsigned short)(zlp.y >> 16))), LOSC,
                             __half2float(__ushort_as_half(
                                 (unsigned short)(zhp.y >> 16))));
            float g0 = fmaf(wv1, z0v, -wv0 * z1v);
            float g1 = fmaf(wv3, z2v, -wv2 * z3v);
            float4 omq = *reinterpret_cast<const float4*>(&sh.om[cb >> 1]);
            d0 = fmaf(g0, omq.x, d0); d1 = fmaf(g0, omq.y, d1);
            d0 = fmaf(g1, omq.z, d0); d1 = fmaf(g1, omq.w, d1);
        }
        if (cB >= 8) { d0 = 0.f; d1 = 0.f; }   // mask mirrored junk cols

        d0 += __shfl_xor(d0, 16, 64);  d0 += __shfl_xor(d0, 32, 64);
        d1 += __shfl_xor(d1, 16, 64);  d1 += __shfl_xor(d1, 32, 64);
        if (l < 8) {
            sh.wred[w][l]     = d0;
            sh.wred[w][l + 8] = d1;
        }
        __syncthreads();

        // publish / consume (packed u64, R14 protocol)
        unsigned long long* pbuf =
            part + ((size_t)(t & 1) * NG + g) * (NS * 16);
        if (tid < 16) {
            float ssum = 0.f;
            #pragma unroll
            for (int w2 = 0; w2 < 16; ++w2) ssum += sh.wred[w2][tid];
            unsigned long long pk =
                (((unsigned long long)(unsigned)(t + 1)) << 32) |
                (unsigned long long)__float_as_uint(ssum);
            __hip_atomic_store(pbuf + s * 16 + tid, pk,
                               __ATOMIC_RELAXED, __HIP_MEMORY_SCOPE_AGENT);
        }
        float val = 0.f;
        if (tid < 64) {
            int sl = tid >> 4, v = tid & 15;
            unsigned long long* addr = pbuf + sl * 16 + v;
            const unsigned long long tgt =
                ((unsigned long long)(unsigned)(t + 1)) << 32;
            unsigned long long pk;
            for (;;) {
                pk = __hip_atomic_load(addr, __ATOMIC_RELAXED,
                                       __HIP_MEMORY_SCOPE_AGENT);
                if (pk >= tgt) break;
                __builtin_amdgcn_s_sleep(1);
            }
            val = __uint_as_float((unsigned)(pk & 0xffffffffull));
            val += __shfl_xor(val, 16, 64);
            val += __shfl_xor(val, 32, 64);
        }
        if (tid < 16) {
            int b = tid & 7, comp = tid >> 3;
            float pi = reinterpret_cast<const float*>(&sh.dpi[b][t])[comp];
            float dtv = fmaf(DXSC, val, pi);
            Sreg += dtv;
            xreg = fminf(fmaxf(xreg + dtv, 0.f), 2.0f);
            reinterpret_cast<float*>(&sh.x[b])[comp] = xreg;
            sh.Sh[t][b][comp] = Sreg;
            sh.xh[t][b][comp] = xreg;
        }
        __syncthreads();
    }

    // epilogue
    {
        int th2 = tid >> 9, b = (tid >> 6) & 7, kk = tid & 63;
        float2 zp = reinterpret_cast<const float2*>(z0)
                        [(size_t)(b0 + b) * KP + 64 * s + kk];
        float2 o2 = sh.om[64 * s + kk];
        float2* zout = reinterpret_cast<float2*>(z_seq)
                       + (size_t)(b0 + b) * NT * KP + (64 * s + kk);
        for (int tt2 = th2 * 64, e = th2 * 64 + 64; tt2 < e; ++tt2) {
            float Sx = sh.Sh[tt2][b][0], Sy = sh.Sh[tt2][b][1];
            float th = o2.x * Sx + o2.y * Sy;
            float sn, cs;
            __sincosf(th, &sn, &cs);
            zout[(size_t)tt2 * KP] =
                make_float2(cs * zp.x - sn * zp.y, sn * zp.x + cs * zp.y);
        }
    }
    if (s == 0) {
        int b = tid >> 7, tt3 = tid & 127;
        float2 xv = *reinterpret_cast<const float2*>(&sh.xh[tt3][b][0]);
        reinterpret_cast<float2*>(x_seq)[(size_t)(b0 + b) * NT + tt3] = xv;
    }
}

// =================== f32 fallback path (R14, proven) ===================

struct __align__(16) ShmF {
    float  zxc[6400];
    float2 dpi[NB][NT];
    float2 om[KP];
    float2 v[KP];
    float  wred[16][16];
    float  Sh[NT][NB][2];
    float  xh[NT][NB][2];
    float2 x[NB];
    float  nred[16];
    float  pad[7168];
};

__attribute__((amdgpu_flat_work_group_size(1024, 1024),
               amdgpu_waves_per_eu(4, 4)))
__global__ void can_f32(
    const float* __restrict__ dx_pi, const float* __restrict__ z0,
    const float* __restrict__ x0, const float* __restrict__ omega,
    const float* __restrict__ A, const float* __restrict__ z0b,
    float* __restrict__ d_out,
    unsigned long long* __restrict__ part)
{
    __shared__ ShmF sh;
    const int tid = threadIdx.x;
    const int g   = blockIdx.x >> 2;
    const int s   = blockIdx.x & 3;
    const int b0  = NB * g;

    float* z_seq = d_out;
    float* x_seq = d_out + (size_t)512 * NT * DD;

    if (dx_pi == nullptr) ((volatile float*)sh.pad)[0] = 1.f;

    {
        int bb = tid >> 7, tt = tid & 127;
        sh.dpi[bb][tt] =
            reinterpret_cast<const float2*>(dx_pi)[(size_t)(b0 + bb) * NT + tt];
    }
    if (tid < KP) sh.om[tid] = reinterpret_cast<const float2*>(omega)[tid];

    float sq = 0.f;
    if (tid < DD) { float f = z0b[tid]; sq = f * f; }
    #pragma unroll
    for (int o = 1; o < 64; o <<= 1) sq += __shfl_xor(sq, o, 64);
    if ((tid & 63) == 0) sh.nred[tid >> 6] = sq;
    __syncthreads();
    float nsq = 0.f;
    #pragma unroll
    for (int w = 0; w < 16; ++w) nsq += sh.nred[w];
    const float zinv = 1.0f / (sqrtf(nsq) + 1e-5f);
    if (tid < KP) {
        float2 vv = reinterpret_cast<const float2*>(z0b)[tid];
        sh.v[tid] = make_float2(vv.x * zinv, vv.y * zinv);
    }

    float xreg = 0.f, Sreg = 0.f;
    if (tid < 16) {
        int b = tid & 7, comp = tid >> 3;
        xreg = x0[(size_t)(b0 + b) * 2 + comp];
        reinterpret_cast<float*>(&sh.x[b])[comp] = xreg;
    }
    __syncthreads();

    const int rq  = tid >> 6;
    const int cq  = tid & 63;
    const int rg0 = 128 * s + 8 * rq;
    const float4* Ap = reinterpret_cast<const float4*>(A)
                       + (size_t)rg0 * 128 + 2 * cq;
    const int zb  = rofs(rg0);
    const int c0  = 8 * cq;
    const int lane = tid & 63;
    const int s5 = (lane >> 5) & 1, s4 = (lane >> 4) & 1;
    const int s3 = (lane >> 3) & 1, s2 = (lane >> 2) & 1;

    for (int t = 0; t < NT; ++t) {
        {
            int k1 = tid >> 2, bq = tid & 3;
            float2 o2 = sh.om[k1];
            float2 vv = sh.v[k1];
            int ro0 = rofs(2 * k1);
            float a0[2], a1[2];
            #pragma unroll
            for (int j = 0; j < 2; ++j) {
                float2 xb = sh.x[2 * bq + j];
                float th = o2.x * xb.x + o2.y * xb.y;
                float sn, cs;
                __sincosf(th, &sn, &cs);
                a0[j] = cs * vv.x - sn * vv.y;
                a1[j] = sn * vv.x + cs * vv.y;
            }
            *reinterpret_cast<float2*>(&sh.zxc[ro0 + 2 * bq]) =
                make_float2(a0[0], a0[1]);
            *reinterpret_cast<float2*>(&sh.zxc[ro0 + 12 + 2 * bq]) =
                make_float2(a1[0], a1[1]);
        }
        __syncthreads();

        #pragma unroll
        for (int h = 0; h < 2; ++h) {
            float4 accA[4], accB[4];
            #pragma unroll
            for (int c = 0; c < 4; ++c) {
                accA[c] = make_float4(0.f, 0.f, 0.f, 0.f);
                accB[c] = make_float4(0.f, 0.f, 0.f, 0.f);
            }
            #pragma unroll
            for (int jr = 0; jr < 8; ++jr) {
                float4 a = Ap[(size_t)jr * 128 + h];
                float4 zA = *reinterpret_cast<const float4*>(
                                &sh.zxc[zb + 12 * jr]);
                float4 zB = *reinterpret_cast<const float4*>(
                                &sh.zxc[zb + 12 * jr + 4]);
                float aw[4];
                aw[0] = a.x; aw[1] = a.y; aw[2] = a.z; aw[3] = a.w;
                #pragma unroll
                for (int c = 0; c < 4; ++c) {
                    accA[c].x = fmaf(aw[c], zA.x, accA[c].x);
                    accA[c].y = fmaf(aw[c], zA.y, accA[c].y);
                    accA[c].z = fmaf(aw[c], zA.z, accA[c].z);
                    accA[c].w = fmaf(aw[c], zA.w, accA[c].w);
                    accB[c].x = fmaf(aw[c], zB.x, accB[c].x);
                    accB[c].y = fmaf(aw[c], zB.y, accB[c].y);
                    accB[c].z = fmaf(aw[c], zB.z, accB[c].z);
                    accB[c].w = fmaf(aw[c], zB.w, accB[c].w);
                }
            }

            float4 d0A = make_float4(0,0,0,0), d0B = d0A;
            float4 d1A = d0A, d1B = d0A;
            float4 omv = *reinterpret_cast<const float4*>(
                             &sh.om[4 * cq + 2 * h]);
            #pragma unroll
            for (int pp = 0; pp < 2; ++pp) {
                int rl = rofs(c0 + 4 * h + 2 * pp);
                float4 zl0 = *reinterpret_cast<const float4*>(&sh.zxc[rl]);
                float4 zl1 = *reinterpret_cast<const float4*>(&sh.zxc[rl + 4]);
                float4 zh0 = *reinterpret_cast<const float4*>(&sh.zxc[rl + 12]);
                float4 zh1 = *reinterpret_cast<const float4*>(&sh.zxc[rl + 16]);
                float4 wl = accA[2 * pp], wh = accA[2 * pp + 1];
                float4 gl = accB[2 * pp], gh = accB[2 * pp + 1];
                float4 gA, gB;
                gA.x = fmaf(wh.x, zl0.x, -wl.x * zh0.x);
                gA.y = fmaf(wh.y, zl0.y, -wl.y * zh0.y);
                gA.z = fmaf(wh.z, zl0.z, -wl.z * zh0.z);
                gA.w = fmaf(wh.w, zl0.w, -wl.w * zh0.w);
                gB.x = fmaf(gh.x, zl1.x, -gl.x * zh1.x);
                gB.y = fmaf(gh.y, zl1.y, -gl.y * zh1.y);
                gB.z = fmaf(gh.z, zl1.z, -gl.z * zh1.z);
                gB.w = fmaf(gh.w, zl1.w, -gl.w * zh1.w);
                float ox = pp ? omv.z : omv.x;
                float oy = pp ? omv.w : omv.y;
                d0A.x = fmaf(gA.x, ox, d0A.x); d1A.x = fmaf(gA.x, oy, d1A.x);
                d0A.y = fmaf(gA.y, ox, d0A.y); d1A.y = fmaf(gA.y, oy, d1A.y);
                d0A.z = fmaf(gA.z, ox, d0A.z); d1A.z = fmaf(gA.z, oy, d1A.z);
                d0A.w = fmaf(gA.w, ox, d0A.w); d1A.w = fmaf(gA.w, oy, d1A.w);
                d0B.x = fmaf(gB.x, ox, d0B.x); d1B.x = fmaf(gB.x, oy, d1B.x);
                d0B.y = fmaf(gB.y, ox, d0B.y); d1B.y = fmaf(gB.y, oy, d1B.y);
                d0B.z = fmaf(gB.z, ox, d0B.z); d1B.z = fmaf(gB.z, oy, d1B.z);
                d0B.w = fmaf(gB.w, ox, d0B.w); d1B.w = fmaf(gB.w, oy, d1B.w);
            }

            {
                float r_[16];
                *reinterpret_cast<float4*>(&r_[0])  = d0A;
                *reinterpret_cast<float4*>(&r_[4])  = d0B;
                *reinterpret_cast<float4*>(&r_[8])  = d1A;
                *reinterpret_cast<float4*>(&r_[12]) = d1B;
                #pragma unroll
                for (int k = 0; k < 8; ++k) {
                    float snd = s5 ? r_[k] : r_[k + 8];
                    float rcv = __shfl_xor(snd, 32, 64);
                    r_[k] = (s5 ? r_[k + 8] : r_[k]) + rcv;
                }
                #pragma unroll
                for (int k = 0; k < 4; ++k) {
                    float snd = s4 ? r_[k] : r_[k + 4];
                    float rcv = __shfl_xor(snd, 16, 64);
                    r_[k] = (s4 ? r_[k + 4] : r_[k]) + rcv;
                }
                #pragma unroll
                for (int k = 0; k < 2; ++k) {
                    float snd = s3 ? r_[k] : r_[k + 2];
                    float rcv = __shfl_xor(snd, 8, 64);
                    r_[k] = (s3 ? r_[k + 2] : r_[k]) + rcv;
                }
                {
                    float snd = s2 ? r_[0] : r_[1];
                    float rcv = __shfl_xor(snd, 4, 64);
                    r_[0] = (s2 ? r_[1] : r_[0]) + rcv;
                }
                r_[0] += __shfl_xor(r_[0], 2, 64);
                r_[0] += __shfl_xor(r_[0], 1, 64);
                if ((lane & 3) == 0) {
                    if (h == 0) sh.wred[rq][lane >> 2] = r_[0];
                    else        sh.wred[rq][lane >> 2] += r_[0];
                }
            }
        }
        __syncthreads();

        unsigned long long* pbuf =
            part + ((size_t)(t & 1) * NG + g) * (NS * 16);
        if (tid < 16) {
            float ssum = 0.f;
            #pragma unroll
            for (int w = 0; w < 16; ++w) ssum += sh.wred[w][tid];
            unsigned long long pk =
                (((unsigned long long)(unsigned)(t + 1)) << 32) |
                (unsigned long long)__float_as_uint(ssum);
            __hip_atomic_store(pbuf + s * 16 + tid, pk,
                               __ATOMIC_RELAXED, __HIP_MEMORY_SCOPE_AGENT);
        }
        float val = 0.f;
        if (tid < 64) {
            int sl = tid >> 4, v = tid & 15;
            unsigned long long* addr = pbuf + sl * 16 + v;
            const unsigned long long tgt =
                ((unsigned long long)(unsigned)(t + 1)) << 32;
            unsigned long long pk;
            for (;;) {
                pk = __hip_atomic_load(addr, __ATOMIC_RELAXED,
                                       __HIP_MEMORY_SCOPE_AGENT);
                if (pk >= tgt) break;
                __builtin_amdgcn_s_sleep(1);
            }
            val = __uint_as_float((unsigned)(pk & 0xffffffffull));
            val += __shfl_xor(val, 16, 64);
            val += __shfl_xor(val, 32, 64);
        }
        if (tid < 16) {
            int b = tid & 7, comp = tid >> 3;
            float pi = reinterpret_cast<const float*>(&sh.dpi[b][t])[comp];
            float dtv = fmaf(0.1f, val, pi);
            Sreg += dtv;
            xreg = fminf(fmaxf(xreg + dtv, 0.f), 2.0f);
            reinterpret_cast<float*>(&sh.x[b])[comp] = xreg;
            sh.Sh[t][b][comp] = Sreg;
            sh.xh[t][b][comp] = xreg;
        }
        __syncthreads();
    }

    {
        int th2 = tid >> 9, b = (tid >> 6) & 7, kk = tid & 63;
        float2 zp = reinterpret_cast<const float2*>(z0)
                        [(size_t)(b0 + b) * KP + 64 * s + kk];
        float2 o2 = sh.om[64 * s + kk];
        float2* zout = reinterpret_cast<float2*>(z_seq)
                       + (size_t)(b0 + b) * NT * KP + (64 * s + kk);
        for (int tt2 = th2 * 64, e = th2 * 64 + 64; tt2 < e; ++tt2) {
            float Sx = sh.Sh[tt2][b][0], Sy = sh.Sh[tt2][b][1];
            float th = o2.x * Sx + o2.y * Sy;
            float sn, cs;
            __sincosf(th, &sn, &cs);
            zout[(size_t)tt2 * KP] =
                make_float2(cs * zp.x - sn * zp.y, sn * zp.x + cs * zp.y);
        }
    }
    if (s == 0) {
        int b = tid >> 7, tt3 = tid & 127;
        float2 xv = *reinterpret_cast<const float2*>(&sh.xh[tt3][b][0]);
        reinterpret_cast<float2*>(x_seq)[(size_t)(b0 + b) * NT + tt3] = xv;
    }
}

extern "C" void kernel_launch(void* const* d_in, const int* in_sizes, int n_in,
                              void* d_out, int out_size, void* d_ws, size_t ws_size,
                              hipStream_t stream) {
    (void)in_sizes; (void)n_in; (void)out_size;
    unsigned long long* part = reinterpret_cast<unsigned long long*>(d_ws);
    hipMemsetAsync(d_ws, 0, PART_BYTES, stream);   // zero exchange tags

    const size_t need = PART_BYTES + 2 * A16_BYTES;   // 64K + 1M
    if (ws_size >= need) {
        unsigned short* Ah = reinterpret_cast<unsigned short*>(
            reinterpret_cast<char*>(d_ws) + PART_BYTES);
        unsigned short* Al = Ah + (size_t)DD * DD;
        hipLaunchKernelGGL(conv_a, dim3(DD * DD / 512), dim3(512), 0, stream,
                           (const float*)d_in[4], Ah, Al);
        hipLaunchKernelGGL(can_mfma, dim3(NBLK), dim3(1024), 0, stream,
                           (const float*)d_in[0], (const float*)d_in[1],
                           (const float*)d_in[2], (const float*)d_in[3],
                           (const float*)d_in[5], (float*)d_out, part, Ah, Al);
    } else {
        hipLaunchKernelGGL(can_f32, dim3(NBLK), dim3(1024), 0, stream,
                           (const float*)d_in[0], (const float*)d_in[1],
                           (const float*)d_in[2], (const float*)d_in[3],
                           (const float*)d_in[4], (const float*)d_in[5],
                           (float*)d_out, part);
    }
}